// Round 14
// baseline (1660.638 us; speedup 1.0000x reference)
//
#include <hip/hip_runtime.h>

#define DIMS 1024
#define NB 1024         // pass-kernel blocks (partials)
#define TPB 256
#define NWAVE 4
#define CB 64           // combine blocks (16 dims each)

#if defined(__has_builtin)
#if __has_builtin(__builtin_amdgcn_sdot8)
#define HAVE_SDOT8 1
#endif
#endif
#ifndef HAVE_SDOT8
#define HAVE_SDOT8 0
#endif

__device__ __forceinline__ float wave_sum(float v) {
#pragma unroll
  for (int s = 32; s; s >>= 1) v += __shfl_xor(v, s, 64);
  return v;
}

__device__ __forceinline__ float wave_max(float v) {
#pragma unroll
  for (int s = 32; s; s >>= 1) v = fmaxf(v, __shfl_xor(v, s, 64));
  return v;
}

__device__ __forceinline__ int nib(unsigned int w, int i) {
  return (int)(w << (28 - 4 * i)) >> 28;
}

// encode 16 f32 (4x float4, qx-order) -> 16 signed int4 nibbles in uint2
__device__ __forceinline__ uint2 enc_i4(const float4* xv, float scale) {
  unsigned int w[2];
#pragma unroll
  for (int h = 0; h < 2; ++h) {
    unsigned int a = 0;
#pragma unroll
    for (int jj = 0; jj < 2; ++jj) {
      float4 t = xv[h * 2 + jj];
      a |= ((unsigned int)((int)rintf(t.x * scale) & 0xF)) << (jj * 16 + 0);
      a |= ((unsigned int)((int)rintf(t.y * scale) & 0xF)) << (jj * 16 + 4);
      a |= ((unsigned int)((int)rintf(t.z * scale) & 0xF)) << (jj * 16 + 8);
      a |= ((unsigned int)((int)rintf(t.w * scale) & 0xF)) << (jj * 16 + 12);
    }
    w[h] = a;
  }
  return make_uint2(w[0], w[1]);
}

// ---------------- f32 pass: fixed-offset softmax (sim in [-1,1], p = exp(sim-1)) ----------
// STEP0: compute invnorm.  WQ: write int4 copy + rowmeta.
template <int STEP0, int WQ>
__global__ __launch_bounds__(TPB) void pass_f32(
    const float* __restrict__ ca3,
    const float* __restrict__ q,
    float* __restrict__ invnorm,
    uint2* __restrict__ qmat,           // [N][64] uint2 (row = 1024 int4 nibbles)
    float2* __restrict__ rowmeta,       // [N] {inv_scale*invnorm, inv_scale}
    float* __restrict__ part_acc,
    float* __restrict__ part_l,
    int rows_per_block) {
  const int tid  = threadIdx.x;
  const int lane = tid & 63;
  const int wv   = tid >> 6;
  const int bid  = blockIdx.x;

  const float4* q4 = (const float4*)q;
  float4 qv[4];
  float qss = 0.f;
#pragma unroll
  for (int j = 0; j < 4; ++j) {
    float4 t = q4[j * 64 + lane];
    qv[j] = t;
    qss += t.x * t.x + t.y * t.y + t.z * t.z + t.w * t.w;
  }
  qss = wave_sum(qss);
  const float inv_qn = 1.0f / fmaxf(sqrtf(qss), 1e-8f);

  const int rpw = rows_per_block >> 2;
  const long long row0 = (long long)bid * rows_per_block + (long long)wv * rpw;

  float l = 0.f;
  float4 acc[4];
#pragma unroll
  for (int j = 0; j < 4; ++j) acc[j] = make_float4(0.f, 0.f, 0.f, 0.f);

  for (int r = 0; r < rpw; r += 2) {
    const long long rowA = row0 + r;
    const long long rowB = rowA + 1;
    const float4* xA4 = (const float4*)(ca3 + rowA * (long long)DIMS);
    const float4* xB4 = (const float4*)(ca3 + rowB * (long long)DIMS);
    float innA = 0.f, innB = 0.f;
    if (!STEP0) { innA = invnorm[rowA]; innB = invnorm[rowB]; }
    float4 xa[4], xb[4];
#pragma unroll
    for (int j = 0; j < 4; ++j) xa[j] = xA4[j * 64 + lane];
#pragma unroll
    for (int j = 0; j < 4; ++j) xb[j] = xB4[j * 64 + lane];

    float dA = 0.f, dB = 0.f, rnA = 0.f, rnB = 0.f, mxA = 0.f, mxB = 0.f;
#pragma unroll
    for (int j = 0; j < 4; ++j) {
      dA += xa[j].x * qv[j].x + xa[j].y * qv[j].y + xa[j].z * qv[j].z + xa[j].w * qv[j].w;
      dB += xb[j].x * qv[j].x + xb[j].y * qv[j].y + xb[j].z * qv[j].z + xb[j].w * qv[j].w;
      if (STEP0) {
        rnA += xa[j].x * xa[j].x + xa[j].y * xa[j].y + xa[j].z * xa[j].z + xa[j].w * xa[j].w;
        rnB += xb[j].x * xb[j].x + xb[j].y * xb[j].y + xb[j].z * xb[j].z + xb[j].w * xb[j].w;
      }
      if (WQ) {
        mxA = fmaxf(mxA, fmaxf(fmaxf(fabsf(xa[j].x), fabsf(xa[j].y)),
                               fmaxf(fabsf(xa[j].z), fabsf(xa[j].w))));
        mxB = fmaxf(mxB, fmaxf(fmaxf(fabsf(xb[j].x), fabsf(xb[j].y)),
                               fmaxf(fabsf(xb[j].z), fabsf(xb[j].w))));
      }
    }
    dA = wave_sum(dA);
    dB = wave_sum(dB);
    if (STEP0) {
      rnA = wave_sum(rnA);
      rnB = wave_sum(rnB);
      innA = 1.0f / fmaxf(sqrtf(rnA), 1e-8f);
      innB = 1.0f / fmaxf(sqrtf(rnB), 1e-8f);
      if (lane == 0) { invnorm[rowA] = innA; invnorm[rowB] = innB; }
    }
    if (WQ) {
      mxA = wave_max(mxA);
      mxB = wave_max(mxB);
      const float scA = 7.0f / fmaxf(mxA, 1e-20f);
      const float scB = 7.0f / fmaxf(mxB, 1e-20f);
      qmat[rowA * 64 + lane] = enc_i4(xa, scA);
      qmat[rowB * 64 + lane] = enc_i4(xb, scB);
      if (lane == 0) {
        const float isA = mxA * (1.0f / 7.0f);
        const float isB = mxB * (1.0f / 7.0f);
        rowmeta[rowA] = make_float2(isA * innA, isA);
        rowmeta[rowB] = make_float2(isB * innB, isB);
      }
    }
    const float pA = __expf(dA * innA * inv_qn - 1.0f);
    const float pB = __expf(dB * innB * inv_qn - 1.0f);
    l += pA + pB;
#pragma unroll
    for (int j = 0; j < 4; ++j) {
      acc[j].x += pA * xa[j].x + pB * xb[j].x;
      acc[j].y += pA * xa[j].y + pB * xb[j].y;
      acc[j].z += pA * xa[j].z + pB * xb[j].z;
      acc[j].w += pA * xa[j].w + pB * xb[j].w;
    }
  }

  // ---- block-level combine ----
  __shared__ float s_l[NWAVE];
  __shared__ float s_lin[NWAVE * DIMS];  // 16 KB
  if (lane == 0) s_l[wv] = l;
#pragma unroll
  for (int j = 0; j < 4; ++j)
    ((float4*)s_lin)[wv * (DIMS / 4) + j * 64 + lane] = acc[j];
  __syncthreads();
  float4 sum = ((float4*)s_lin)[tid];
#pragma unroll
  for (int w = 1; w < NWAVE; ++w) {
    float4 b = ((float4*)s_lin)[w * (DIMS / 4) + tid];
    sum.x += b.x; sum.y += b.y; sum.z += b.z; sum.w += b.w;
  }
  ((float4*)part_acc)[bid * (DIMS / 4) + tid] = sum;
  if (tid == 0) part_l[bid] = s_l[0] + s_l[1] + s_l[2] + s_l[3];
}

// ---------------- int4 pass: pair-packed rows, 5-step half-wave reduce ----------------
__device__ __forceinline__ void procpair(const uint4* u, const float2* mt,
                                         unsigned int qa0, unsigned int qa1,
                                         unsigned int qb0, unsigned int qb1,
                                         float qs2, float& l, int* acc) {
  int d[4];
#pragma unroll
  for (int k = 0; k < 4; ++k) {
#if HAVE_SDOT8
    int t = __builtin_amdgcn_sdot8((int)u[k].x, (int)qa0, 0, false);
    t = __builtin_amdgcn_sdot8((int)u[k].y, (int)qa1, t, false);
    t = __builtin_amdgcn_sdot8((int)u[k].z, (int)qb0, t, false);
    t = __builtin_amdgcn_sdot8((int)u[k].w, (int)qb1, t, false);
#else
    int t = 0;
#pragma unroll
    for (int i = 0; i < 8; ++i) t += __mul24(nib(u[k].x, i), nib(qa0, i));
#pragma unroll
    for (int i = 0; i < 8; ++i) t += __mul24(nib(u[k].y, i), nib(qa1, i));
#pragma unroll
    for (int i = 0; i < 8; ++i) t += __mul24(nib(u[k].z, i), nib(qb0, i));
#pragma unroll
    for (int i = 0; i < 8; ++i) t += __mul24(nib(u[k].w, i), nib(qb1, i));
#endif
    d[k] = t;
  }
  // 5-step half-wave butterfly: lanes<32 end with row 2p sum, lanes>=32 with row 2p+1
#pragma unroll
  for (int s = 16; s; s >>= 1)
#pragma unroll
    for (int k = 0; k < 4; ++k) d[k] += __shfl_xor(d[k], s, 64);
#pragma unroll
  for (int k = 0; k < 4; ++k) {
    const float p = __expf((float)d[k] * mt[k].x * qs2 - 1.0f);
    l += p;
    const int pai = (int)(p * mt[k].y * 1048576.0f + 0.5f);  // < 2^24
#pragma unroll
    for (int i = 0; i < 8; ++i) acc[i]      += __mul24(pai, nib(u[k].x, i));
#pragma unroll
    for (int i = 0; i < 8; ++i) acc[8 + i]  += __mul24(pai, nib(u[k].y, i));
#pragma unroll
    for (int i = 0; i < 8; ++i) acc[16 + i] += __mul24(pai, nib(u[k].z, i));
#pragma unroll
    for (int i = 0; i < 8; ++i) acc[24 + i] += __mul24(pai, nib(u[k].w, i));
  }
}

__global__ __launch_bounds__(TPB, 4) void pass_i4(
    const uint4* __restrict__ qmat4,    // pair (2 rows) = 64 uint4 (1024 B)
    const float* __restrict__ q,
    const float2* __restrict__ rowmeta, // {inv_scale*invnorm, inv_scale}
    float* __restrict__ part_acc,
    float* __restrict__ part_l,
    int rows_per_block) {
  const int tid  = threadIdx.x;
  const int lane = tid & 63;
  const int wv   = tid >> 6;
  const int bid  = blockIdx.x;
  const int h    = lane >> 5;   // which row of the pair this lane serves
  const int m    = lane & 31;   // pair-column index: this lane holds uint2-cols {2m, 2m+1}

  // ---- q fragment (qx-order, col = lane) + quantize ----
  const float4* q4 = (const float4*)q;
  float qx[16];
  float qss = 0.f, qmx = 0.f;
#pragma unroll
  for (int j = 0; j < 4; ++j) {
    float4 t = q4[j * 64 + lane];
    qx[4 * j + 0] = t.x; qx[4 * j + 1] = t.y; qx[4 * j + 2] = t.z; qx[4 * j + 3] = t.w;
    qss += t.x * t.x + t.y * t.y + t.z * t.z + t.w * t.w;
    qmx = fmaxf(qmx, fmaxf(fmaxf(fabsf(t.x), fabsf(t.y)), fmaxf(fabsf(t.z), fabsf(t.w))));
  }
  qss = wave_sum(qss);
  qmx = wave_max(qmx);
  const float inv_qn = 1.0f / fmaxf(sqrtf(qss), 1e-8f);
  const float sq = 7.0f / fmaxf(qmx, 1e-20f);
  unsigned int qq0 = 0, qq1 = 0;
#pragma unroll
  for (int i = 0; i < 8; ++i)
    qq0 |= ((unsigned int)((int)rintf(qx[i] * sq) & 0xF)) << (4 * i);
#pragma unroll
  for (int i = 0; i < 8; ++i)
    qq1 |= ((unsigned int)((int)rintf(qx[8 + i] * sq) & 0xF)) << (4 * i);
  const float qs2 = (qmx * (1.0f / 7.0f)) * inv_qn;

  // redistribute q nibbles to pair-column layout: lane needs cols 2m and 2m+1
  const unsigned int qa0 = (unsigned int)__shfl((int)qq0, 2 * m, 64);
  const unsigned int qa1 = (unsigned int)__shfl((int)qq1, 2 * m, 64);
  const unsigned int qb0 = (unsigned int)__shfl((int)qq0, 2 * m + 1, 64);
  const unsigned int qb1 = (unsigned int)__shfl((int)qq1, 2 * m + 1, 64);

  // ---- main loop: 32 pairs per wave, groups of 4 pairs, A/B prefetch ----
  const long long pair0 =
      ((long long)bid * rows_per_block + (long long)wv * (rows_per_block >> 2)) >> 1;
  const uint4* base = qmat4 + pair0 * 64;
  const float2* metab = rowmeta + pair0 * 2;

  float l = 0.f;
  int acc[32];
#pragma unroll
  for (int i = 0; i < 32; ++i) acc[i] = 0;

  uint4 ua[4], ub[4];
  float2 ma[4], mb[4];
#pragma unroll
  for (int k = 0; k < 4; ++k) { ua[k] = base[k * 64 + lane]; ma[k] = metab[k * 2 + h]; }

  const int ng = rows_per_block >> 5;  // groups of 4 pairs (8 rows): 8
  for (int g = 0; g < ng; g += 2) {
    const int gB = g + 1;
    const int gA2 = (g + 2 < ng) ? (g + 2) : 0;
#pragma unroll
    for (int k = 0; k < 4; ++k) {
      ub[k] = base[(gB * 4 + k) * 64 + lane];
      mb[k] = metab[(gB * 4 + k) * 2 + h];
    }
    procpair(ua, ma, qa0, qa1, qb0, qb1, qs2, l, acc);
#pragma unroll
    for (int k = 0; k < 4; ++k) {
      ua[k] = base[(gA2 * 4 + k) * 64 + lane];
      ma[k] = metab[(gA2 * 4 + k) * 2 + h];
    }
    procpair(ub, mb, qa0, qa1, qb0, qb1, qs2, l, acc);
  }

  // ---- epilogue: fold halves, block combine -> part_acc / part_l ----
  const float lt = wave_sum(l) * 0.03125f;  // 32 lanes per half held identical p
#pragma unroll
  for (int i = 0; i < 32; ++i) acc[i] += __shfl_xor(acc[i], 32, 64);

  __shared__ float s_l[NWAVE];
  __shared__ float s_lin[NWAVE * DIMS];  // 16 KB
  if (lane == 0) s_l[wv] = lt;
  const float ds = 9.5367431640625e-7f;  // 2^-20
  if (lane < 32) {
#pragma unroll
    for (int j = 0; j < 4; ++j) {
      ((float4*)s_lin)[wv * (DIMS / 4) + j * 64 + 2 * m] =
          make_float4((float)acc[4 * j + 0] * ds, (float)acc[4 * j + 1] * ds,
                      (float)acc[4 * j + 2] * ds, (float)acc[4 * j + 3] * ds);
      ((float4*)s_lin)[wv * (DIMS / 4) + j * 64 + 2 * m + 1] =
          make_float4((float)acc[16 + 4 * j + 0] * ds, (float)acc[16 + 4 * j + 1] * ds,
                      (float)acc[16 + 4 * j + 2] * ds, (float)acc[16 + 4 * j + 3] * ds);
    }
  }
  __syncthreads();
  float4 sum = ((float4*)s_lin)[tid];
#pragma unroll
  for (int w = 1; w < NWAVE; ++w) {
    float4 b = ((float4*)s_lin)[w * (DIMS / 4) + tid];
    sum.x += b.x; sum.y += b.y; sum.z += b.z; sum.w += b.w;
  }
  ((float4*)part_acc)[bid * (DIMS / 4) + tid] = sum;
  if (tid == 0) part_l[bid] = s_l[0] + s_l[1] + s_l[2] + s_l[3];
}

// ---------------- combine partials -> retrieved -> blend into current ----------------
__global__ __launch_bounds__(256) void combine_k(
    const float* __restrict__ part_acc,
    const float* __restrict__ part_l,
    float* __restrict__ cur) {
  const int tid  = threadIdx.x;
  const int lane = tid & 63;
  const int wv   = tid >> 6;
  __shared__ float s_w[NWAVE];

  float lz = 0.f;
  for (int p = tid; p < NB; p += 256) lz += part_l[p];
  lz = wave_sum(lz);
  if (lane == 0) s_w[wv] = lz;
  __syncthreads();
  const float invZ = 1.0f / (s_w[0] + s_w[1] + s_w[2] + s_w[3]);

  const int base = blockIdx.x * 16;
  const int d = tid & 15;
  const int g = tid >> 4;
  float a = 0.f;
  for (int p = g; p < NB; p += 16) a += part_acc[p * DIMS + base + d];
  __shared__ float s_a[16][17];
  s_a[g][d] = a;
  __syncthreads();
#pragma unroll
  for (int s = 8; s; s >>= 1) {
    if (g < s) s_a[g][d] += s_a[g + s][d];
    __syncthreads();
  }
  if (tid < 16) {
    const float retrieved = s_a[0][tid] * invZ;
    const float c = cur[base + tid];
    cur[base + tid] = 0.8f * retrieved + 0.2f * c;
  }
}

// ---------------- init: DG thresholding ----------------
__global__ void init_k(const float* __restrict__ iso, float* __restrict__ cur) {
  const int d = blockIdx.x * blockDim.x + threadIdx.x;
  if (d < DIMS) {
    const float v = iso[d];
    cur[d] = (v > 0.1f) ? v : 0.f;
  }
}

// ---------------- final: write current + mismatch ----------------
__global__ __launch_bounds__(256) void final_k(const float* __restrict__ iso,
                                               const float* __restrict__ cur,
                                               float* __restrict__ out) {
  const int tid  = threadIdx.x;
  const int lane = tid & 63;
  const int wv   = tid >> 6;
  float ss = 0.f;
  for (int d = tid; d < DIMS; d += 256) {
    const float c = cur[d];
    out[d] = c;
    const float df = iso[d] - c;
    ss += df * df;
  }
  ss = wave_sum(ss);
  __shared__ float s_w[NWAVE];
  if (lane == 0) s_w[wv] = ss;
  __syncthreads();
  if (tid == 0) out[DIMS] = (s_w[0] + s_w[1] + s_w[2] + s_w[3]) * (1.0f / (float)DIMS);
}

extern "C" void kernel_launch(void* const* d_in, const int* in_sizes, int n_in,
                              void* d_out, int out_size, void* d_ws, size_t ws_size,
                              hipStream_t stream) {
  const float* iso = (const float*)d_in[0];
  const float* ca3 = (const float*)d_in[1];
  float* out = (float*)d_out;
  const int N = in_sizes[1] / DIMS;  // 262144

  // ws layout (floats): cur[1024] | part_l[NB] | part_acc[NB*1024] | invnorm[N]
  //                     | rowmeta float2[N] | qmat uint2[N*64]
  float* ws       = (float*)d_ws;
  float* cur      = ws;
  float* part_l   = ws + DIMS;
  float* part_acc = ws + DIMS + NB;
  float* invnorm  = ws + DIMS + NB + NB * DIMS;
  float2* rowmeta = (float2*)(invnorm + N);
  uint2* qmat     = (uint2*)(invnorm + N + 2 * (size_t)N);

  const size_t base_bytes = (size_t)(DIMS + NB + NB * DIMS + N) * 4;
  const size_t need_bytes = base_bytes + (size_t)N * 8 + (size_t)N * 512;
  const bool use_i4 = (ws_size >= need_bytes);

  const int rows_per_block = N / NB;  // 256

  init_k<<<(DIMS + 255) / 256, 256, 0, stream>>>(iso, cur);
  if (use_i4) {
    pass_f32<1, 1><<<NB, TPB, 0, stream>>>(ca3, cur, invnorm, qmat, rowmeta,
                                           part_acc, part_l, rows_per_block);
    combine_k<<<CB, 256, 0, stream>>>(part_acc, part_l, cur);
    for (int s = 1; s < 5; ++s) {
      pass_i4<<<NB, TPB, 0, stream>>>((const uint4*)qmat, cur, rowmeta,
                                      part_acc, part_l, rows_per_block);
      combine_k<<<CB, 256, 0, stream>>>(part_acc, part_l, cur);
    }
  } else {
    for (int s = 0; s < 5; ++s) {
      if (s == 0)
        pass_f32<1, 1><<<NB, TPB, 0, stream>>>(ca3, cur, invnorm, qmat, rowmeta,
                                               part_acc, part_l, rows_per_block);
      else
        pass_f32<0, 0><<<NB, TPB, 0, stream>>>(ca3, cur, invnorm, qmat, rowmeta,
                                               part_acc, part_l, rows_per_block);
      combine_k<<<CB, 256, 0, stream>>>(part_acc, part_l, cur);
    }
  }
  final_k<<<1, 256, 0, stream>>>(iso, cur, out);
}